// Round 1
// baseline (1287.431 us; speedup 1.0000x reference)
//
#include <hip/hip_runtime.h>
#include <stdint.h>

#define B_ 2
#define S_ 2048
#define D_ 4096
#define H_ 32
#define KVH_ 8
#define HD_ 128
#define QKVN 6144          // H*HD + 2*KVH*HD
#define OHD 4096           // H*HD
#define ATTN_MULT 0.08838834764831845f
#define MAX_ATTN 30.0f

typedef __attribute__((ext_vector_type(8))) short short8;
typedef __attribute__((ext_vector_type(4))) float f32x4;

__device__ __forceinline__ unsigned short f2bf(float x) {
  union { float f; uint32_t u; } v; v.f = x;
  uint32_t r = v.u + 0x7FFFu + ((v.u >> 16) & 1u);
  return (unsigned short)(r >> 16);
}
__device__ __forceinline__ float bf2f(unsigned short h) {
  union { uint32_t u; float f; } v; v.u = ((uint32_t)h) << 16;
  return v.f;
}
__device__ __forceinline__ uint32_t packbf(float lo, float hi) {
  return (uint32_t)f2bf(lo) | ((uint32_t)f2bf(hi) << 16);
}

// ---------------- cos/sin table: cs[s][d] = (cos(s*invfreq_d), sin(...)) -----
__global__ void k_cstab(float2* cs) {
  int idx = blockIdx.x * 256 + threadIdx.x;   // S_*64 entries
  int d = idx & 63, s = idx >> 6;
  const float L2_10000 = 13.287712379549449f; // log2(10000)
  float inv = exp2f(-(float)d * (L2_10000 / 64.0f));
  float f = (float)s * inv;
  cs[idx] = make_float2(cosf(f), sinf(f));
}

// ---------------- fp32 -> bf16 elementwise (vectorized) ----------------------
__global__ void k_cvt(const float* __restrict__ x, unsigned short* __restrict__ y, int n4) {
  int i = blockIdx.x * blockDim.x + threadIdx.x;
  int stride = gridDim.x * blockDim.x;
  for (; i < n4; i += stride) {
    float4 v = ((const float4*)x)[i];
    ushort4 o;
    o.x = f2bf(v.x); o.y = f2bf(v.y); o.z = f2bf(v.z); o.w = f2bf(v.w);
    ((ushort4*)y)[i] = o;
  }
}

// ---------------- W [K][N] fp32 -> WT [N][K] bf16 (transpose-convert) --------
__global__ void k_transpose(const float* __restrict__ W, unsigned short* __restrict__ WT,
                            int K, int N) {
  __shared__ float tile[32][33];
  int n0 = blockIdx.x * 32, k0 = blockIdx.y * 32;
  int tx = threadIdx.x, ty = threadIdx.y;   // block (32,8)
#pragma unroll
  for (int j = 0; j < 4; j++)
    tile[ty + j * 8][tx] = W[(size_t)(k0 + ty + j * 8) * N + n0 + tx];
  __syncthreads();
#pragma unroll
  for (int j = 0; j < 4; j++)
    WT[(size_t)(n0 + ty + j * 8) * K + k0 + tx] = f2bf(tile[tx][ty + j * 8]);
}

// ---------------- RoPE in-place on qkv (Q cols 0..4095, K cols 4096..5119) ---
__global__ void k_rope(unsigned short* __restrict__ qkv, const float2* __restrict__ cs) {
  int row = blockIdx.x;                         // b*S + s
  int t = blockIdx.y * 256 + threadIdx.x;       // [0, 2560)
  int head = t >> 6, d = t & 63;
  int col = head < H_ ? head * HD_ + d : D_ + (head - H_) * HD_ + d;
  unsigned short* p = qkv + (size_t)row * QKVN + col;
  int s = row & (S_ - 1);
  float2 c = cs[s * 64 + d];
  float x1 = bf2f(p[0]), x2 = bf2f(p[64]);
  p[0]  = f2bf(x1 * c.x - x2 * c.y);
  p[64] = f2bf(x2 * c.x + x1 * c.y);
}

// ---------------- bf16 GEMM, m97 structure: C[M][N] = A[M][K] * Bt[N][K]^T ---
template <bool OUT_BF16>
__global__ __launch_bounds__(256) void k_gemm(const unsigned short* __restrict__ A,
                                              const unsigned short* __restrict__ Bt,
                                              void* __restrict__ Cout,
                                              int M, int N, int K) {
  __shared__ unsigned short As[128 * 32];
  __shared__ unsigned short Bs[128 * 32];
  const int tid = threadIdx.x;
  const int wv = tid >> 6, lane = tid & 63;
  const int lg = lane >> 4, lq = lane & 15;
  const int bm = blockIdx.y * 128, bn = blockIdx.x * 128;
  const int wm = (wv >> 1) * 64, wn = (wv & 1) * 64;
  const int r0 = wv * 16 + (lane >> 2);   // staging row within pass
  const int kk = (lane & 3) * 8;          // staging k within pass

  f32x4 acc[4][4] = {};

  for (int k0 = 0; k0 < K; k0 += 32) {
#pragma unroll
    for (int p = 0; p < 2; p++) {
      int r = p * 64 + r0;
      __builtin_amdgcn_global_load_lds(
          (const __attribute__((address_space(1))) void*)(A + (size_t)(bm + r) * K + k0 + kk),
          (__attribute__((address_space(3))) void*)((char*)As + p * 4096 + wv * 1024),
          16, 0, 0);
      __builtin_amdgcn_global_load_lds(
          (const __attribute__((address_space(1))) void*)(Bt + (size_t)(bn + r) * K + k0 + kk),
          (__attribute__((address_space(3))) void*)((char*)Bs + p * 4096 + wv * 1024),
          16, 0, 0);
    }
    __syncthreads();
    short8 a[4], b[4];
#pragma unroll
    for (int f = 0; f < 4; f++) {
      a[f] = *(const short8*)&As[(wm + f * 16 + lq) * 32 + lg * 8];
      b[f] = *(const short8*)&Bs[(wn + f * 16 + lq) * 32 + lg * 8];
    }
#pragma unroll
    for (int i = 0; i < 4; i++)
#pragma unroll
      for (int j = 0; j < 4; j++)
        acc[i][j] = __builtin_amdgcn_mfma_f32_16x16x32_bf16(a[i], b[j], acc[i][j], 0, 0, 0);
    __syncthreads();
  }

#pragma unroll
  for (int i = 0; i < 4; i++)
#pragma unroll
    for (int j = 0; j < 4; j++) {
      int row = bm + wm + i * 16 + lg * 4;
      int col = bn + wn + j * 16 + lq;
#pragma unroll
      for (int t = 0; t < 4; t++) {
        float v = acc[i][j][t];
        if (OUT_BF16)
          ((unsigned short*)Cout)[(size_t)(row + t) * N + col] = f2bf(v);
        else
          ((float*)Cout)[(size_t)(row + t) * N + col] = v;
      }
    }
}

// ---------------- flash attention, 1 wave/block, QBLK=32, KVBLK=32 -----------
// swapped QK^T: st = mfma(K_rows, Q^T) -> S^T[kv][q]; softmax per q is a
// 4-lane reduce (shfl_xor 16,32); P exchanged into the x32 A-frag layout.
__device__ __forceinline__ float softcap(float s) {
  float x = s * (ATTN_MULT / MAX_ATTN);
  x = fminf(fmaxf(x, -15.f), 15.f);
  float e = __expf(2.0f * x);
  return MAX_ATTN * ((e - 1.0f) / (e + 1.0f));
}

__global__ __launch_bounds__(64) void k_attn(const unsigned short* __restrict__ qkv,
                                             unsigned short* __restrict__ out) {
  const int lane = threadIdx.x;
  const int lg = lane >> 4, lq = lane & 15;
  const int q0 = blockIdx.x * 32;
  const int h = blockIdx.y;
  const int b = blockIdx.z;
  const int kh = h >> 2;   // GQA groups = 4

  const unsigned short* Qb = qkv + (size_t)(b * S_) * QKVN + h * HD_;
  const unsigned short* Kb = qkv + (size_t)(b * S_) * QKVN + D_ + kh * HD_;
  const unsigned short* Vb = qkv + (size_t)(b * S_) * QKVN + D_ + KVH_ * HD_ + kh * HD_;

  short8 qf[2][4];
#pragma unroll
  for (int u = 0; u < 2; u++)
#pragma unroll
    for (int c = 0; c < 4; c++)
      qf[u][c] = *(const short8*)(Qb + (size_t)(q0 + u * 16 + lq) * QKVN + c * 32 + lg * 8);

  float m[2] = {-1e30f, -1e30f}, l[2] = {0.f, 0.f};
  f32x4 o[2][8] = {};

  const int kv_end = q0 + 32;
  for (int kv0 = 0; kv0 < kv_end; kv0 += 32) {
    short8 ka[2][4];
#pragma unroll
    for (int sI = 0; sI < 2; sI++)
#pragma unroll
      for (int c = 0; c < 4; c++)
        ka[sI][c] = *(const short8*)(Kb + (size_t)(kv0 + sI * 16 + lq) * QKVN + c * 32 + lg * 8);

    short8 vf[8];
#pragma unroll
    for (int fd = 0; fd < 8; fd++)
#pragma unroll
      for (int j = 0; j < 8; j++)
        vf[fd][j] = (short)Vb[(size_t)(kv0 + lg * 8 + j) * QKVN + fd * 16 + lq];

#pragma unroll
    for (int u = 0; u < 2; u++) {
      f32x4 stA = {}, stB = {};
#pragma unroll
      for (int c = 0; c < 4; c++) {
        stA = __builtin_amdgcn_mfma_f32_16x16x32_bf16(ka[0][c], qf[u][c], stA, 0, 0, 0);
        stB = __builtin_amdgcn_mfma_f32_16x16x32_bf16(ka[1][c], qf[u][c], stB, 0, 0, 0);
      }
      // lane holds S^T[kv0 + lg*4 + i][q0 + u*16 + lq] (stA) and +16 (stB)
      const int gq = q0 + u * 16 + lq;
      float w[8];
#pragma unroll
      for (int i = 0; i < 4; i++) {
        w[i]     = (kv0 + lg * 4 + i > gq)      ? -1e30f : softcap(stA[i]);
        w[4 + i] = (kv0 + 16 + lg * 4 + i > gq) ? -1e30f : softcap(stB[i]);
      }
      float mt = w[0];
#pragma unroll
      for (int i = 1; i < 8; i++) mt = fmaxf(mt, w[i]);
      mt = fmaxf(mt, __shfl_xor(mt, 16));
      mt = fmaxf(mt, __shfl_xor(mt, 32));
      float mnew = fmaxf(m[u], mt);
      float scale = __expf(m[u] - mnew);
      float p[8], ps = 0.f;
#pragma unroll
      for (int i = 0; i < 8; i++) { p[i] = __expf(w[i] - mnew); ps += p[i]; }
      ps += __shfl_xor(ps, 16);
      ps += __shfl_xor(ps, 32);
      l[u] = l[u] * scale + ps;
      m[u] = mnew;

      float sc[4];
#pragma unroll
      for (int t = 0; t < 4; t++)
        sc[t] = __shfl(scale, (lane & 48) + lg * 4 + t, 64);
#pragma unroll
      for (int fd = 0; fd < 8; fd++)
#pragma unroll
        for (int t = 0; t < 4; t++) o[u][fd][t] *= sc[t];

      // P exchange -> A-frag: lane needs P[lq][kv0 + 8*lg + j], j=0..7
      uint32_t a01 = packbf(p[0], p[1]), a23 = packbf(p[2], p[3]);
      uint32_t b01 = packbf(p[4], p[5]), b23 = packbf(p[6], p[7]);
      int g0 = (lg & 1) << 1;
      int src0 = (g0 << 4) | lq;
      int src1 = ((g0 + 1) << 4) | lq;
      uint32_t wA0 = __shfl(a01, src0, 64), wB0 = __shfl(b01, src0, 64);
      uint32_t wA1 = __shfl(a23, src0, 64), wB1 = __shfl(b23, src0, 64);
      uint32_t wA2 = __shfl(a01, src1, 64), wB2 = __shfl(b01, src1, 64);
      uint32_t wA3 = __shfl(a23, src1, 64), wB3 = __shfl(b23, src1, 64);
      bool useB = lg >= 2;
      union { short8 v; uint32_t w4[4]; } pa;
      pa.w4[0] = useB ? wB0 : wA0;
      pa.w4[1] = useB ? wB1 : wA1;
      pa.w4[2] = useB ? wB2 : wA2;
      pa.w4[3] = useB ? wB3 : wA3;
#pragma unroll
      for (int fd = 0; fd < 8; fd++)
        o[u][fd] = __builtin_amdgcn_mfma_f32_16x16x32_bf16(pa.v, vf[fd], o[u][fd], 0, 0, 0);
    }
  }

#pragma unroll
  for (int u = 0; u < 2; u++) {
    float li[4];
#pragma unroll
    for (int t = 0; t < 4; t++)
      li[t] = __shfl(l[u], (lane & 48) + lg * 4 + t, 64);
#pragma unroll
    for (int fd = 0; fd < 8; fd++)
#pragma unroll
      for (int t = 0; t < 4; t++) {
        int row = q0 + u * 16 + lg * 4 + t;
        int col = h * HD_ + fd * 16 + lq;
        out[(size_t)(b * S_ + row) * OHD + col] = f2bf(o[u][fd][t] / li[t]);
      }
  }
}

// ---------------------------------------------------------------------------
extern "C" void kernel_launch(void* const* d_in, const int* in_sizes, int n_in,
                              void* d_out, int out_size, void* d_ws, size_t ws_size,
                              hipStream_t stream) {
  const float* hs = (const float*)d_in[0];
  const float* Wq = (const float*)d_in[3];
  const float* Wk = (const float*)d_in[4];
  const float* Wv = (const float*)d_in[5];
  const float* Wo = (const float*)d_in[6];

  char* ws = (char*)d_ws;
  unsigned short* WqkvT = (unsigned short*)ws;                         // 48MB; reused as WoT
  unsigned short* hsb   = (unsigned short*)(ws + 50331648);            // 32MB; reused as attn_out
  float2* cs            = (float2*)(ws + 50331648 + 33554432);         // 1MB
  unsigned short* qkv   = (unsigned short*)d_out;                      // 48MB inside d_out (64MB)
  unsigned short* WoT   = WqkvT;
  unsigned short* attn  = hsb;

  k_cstab<<<dim3((S_ * 64) / 256), 256, 0, stream>>>(cs);
  k_transpose<<<dim3(4096 / 32, 4096 / 32), dim3(32, 8), 0, stream>>>(Wq, WqkvT, 4096, 4096);
  k_transpose<<<dim3(1024 / 32, 4096 / 32), dim3(32, 8), 0, stream>>>(Wk, WqkvT + (size_t)4096 * 4096, 4096, 1024);
  k_transpose<<<dim3(1024 / 32, 4096 / 32), dim3(32, 8), 0, stream>>>(Wv, WqkvT + (size_t)5120 * 4096, 4096, 1024);
  k_cvt<<<2048, 256, 0, stream>>>(hs, hsb, (B_ * S_ * D_) / 4);
  k_gemm<true><<<dim3(QKVN / 128, (B_ * S_) / 128), 256, 0, stream>>>(hsb, WqkvT, qkv, B_ * S_, QKVN, D_);
  k_rope<<<dim3(B_ * S_, 10), 256, 0, stream>>>(qkv, cs);
  k_transpose<<<dim3(4096 / 32, 4096 / 32), dim3(32, 8), 0, stream>>>(Wo, WoT, 4096, 4096);
  k_attn<<<dim3(S_ / 32, H_, B_), 64, 0, stream>>>(qkv, attn);
  k_gemm<false><<<dim3(D_ / 128, (B_ * S_) / 128), 256, 0, stream>>>(attn, WoT, d_out, B_ * S_, D_, D_);
}

// Round 2
// 1160.680 us; speedup vs baseline: 1.1092x; 1.1092x over previous
//
#include <hip/hip_runtime.h>
#include <stdint.h>

#define B_ 2
#define S_ 2048
#define D_ 4096
#define H_ 32
#define KVH_ 8
#define HD_ 128
#define QKVN 6144          // H*HD + 2*KVH*HD
#define OHD 4096           // H*HD
#define ATTN_MULT 0.08838834764831845f
#define MAX_ATTN 30.0f

typedef __attribute__((ext_vector_type(8))) short short8;
typedef __attribute__((ext_vector_type(4))) float f32x4;

__device__ __forceinline__ unsigned short f2bf(float x) {
  union { float f; uint32_t u; } v; v.f = x;
  uint32_t r = v.u + 0x7FFFu + ((v.u >> 16) & 1u);
  return (unsigned short)(r >> 16);
}
__device__ __forceinline__ float bf2f(unsigned short h) {
  union { uint32_t u; float f; } v; v.u = ((uint32_t)h) << 16;
  return v.f;
}
__device__ __forceinline__ uint32_t packbf(float lo, float hi) {
  return (uint32_t)f2bf(lo) | ((uint32_t)f2bf(hi) << 16);
}

// ---------------- cos/sin table: cs[s][d] = (cos(s*invfreq_d), sin(...)) -----
__global__ void k_cstab(float2* cs) {
  int idx = blockIdx.x * 256 + threadIdx.x;   // S_*64 entries
  int d = idx & 63, s = idx >> 6;
  const float L2_10000 = 13.287712379549449f; // log2(10000)
  float inv = exp2f(-(float)d * (L2_10000 / 64.0f));
  float f = (float)s * inv;
  cs[idx] = make_float2(cosf(f), sinf(f));
}

// ---------------- fp32 -> bf16 elementwise (vectorized) ----------------------
__global__ void k_cvt(const float* __restrict__ x, unsigned short* __restrict__ y, int n4) {
  int i = blockIdx.x * blockDim.x + threadIdx.x;
  int stride = gridDim.x * blockDim.x;
  for (; i < n4; i += stride) {
    float4 v = ((const float4*)x)[i];
    ushort4 o;
    o.x = f2bf(v.x); o.y = f2bf(v.y); o.z = f2bf(v.z); o.w = f2bf(v.w);
    ((ushort4*)y)[i] = o;
  }
}

// ---------------- W [K][N] fp32 -> WT [N][K] bf16 (transpose-convert) --------
__global__ void k_transpose(const float* __restrict__ W, unsigned short* __restrict__ WT,
                            int K, int N) {
  __shared__ float tile[32][33];
  int n0 = blockIdx.x * 32, k0 = blockIdx.y * 32;
  int tx = threadIdx.x, ty = threadIdx.y;   // block (32,8)
#pragma unroll
  for (int j = 0; j < 4; j++)
    tile[ty + j * 8][tx] = W[(size_t)(k0 + ty + j * 8) * N + n0 + tx];
  __syncthreads();
#pragma unroll
  for (int j = 0; j < 4; j++)
    WT[(size_t)(n0 + ty + j * 8) * K + k0 + tx] = f2bf(tile[tx][ty + j * 8]);
}

// ---------------- V section of qkv -> vT[b][kh*HD + hd][s] (bf16) ------------
__global__ void k_vt(const unsigned short* __restrict__ qkv, unsigned short* __restrict__ vT) {
  __shared__ unsigned short tile[32][34];
  int c0 = blockIdx.x * 32;     // V column (kh*HD+hd), 0..1023
  int s0 = blockIdx.y * 32;     // sequence pos
  int b  = blockIdx.z;
  int tx = threadIdx.x, ty = threadIdx.y;   // block (32,8)
#pragma unroll
  for (int j = 0; j < 4; j++)
    tile[ty + j * 8][tx] =
        qkv[(size_t)(b * S_ + s0 + ty + j * 8) * QKVN + D_ + KVH_ * HD_ + c0 + tx];
  __syncthreads();
#pragma unroll
  for (int j = 0; j < 4; j++)
    vT[(size_t)(b * KVH_ * HD_ + c0 + ty + j * 8) * S_ + s0 + tx] = tile[tx][ty + j * 8];
}

// ---------------- RoPE in-place on qkv (Q cols 0..4095, K cols 4096..5119) ---
__global__ void k_rope(unsigned short* __restrict__ qkv, const float2* __restrict__ cs) {
  int row = blockIdx.x;                         // b*S + s
  int t = blockIdx.y * 256 + threadIdx.x;       // [0, 2560)
  int head = t >> 6, d = t & 63;
  int col = head < H_ ? head * HD_ + d : D_ + (head - H_) * HD_ + d;
  unsigned short* p = qkv + (size_t)row * QKVN + col;
  int s = row & (S_ - 1);
  float2 c = cs[s * 64 + d];
  float x1 = bf2f(p[0]), x2 = bf2f(p[64]);
  p[0]  = f2bf(x1 * c.x - x2 * c.y);
  p[64] = f2bf(x2 * c.x + x1 * c.y);
}

// ---------------- bf16 GEMM, m97 structure: C[M][N] = A[M][K] * Bt[N][K]^T ---
template <bool OUT_BF16>
__global__ __launch_bounds__(256) void k_gemm(const unsigned short* __restrict__ A,
                                              const unsigned short* __restrict__ Bt,
                                              void* __restrict__ Cout,
                                              int M, int N, int K) {
  __shared__ unsigned short As[128 * 32];
  __shared__ unsigned short Bs[128 * 32];
  const int tid = threadIdx.x;
  const int wv = tid >> 6, lane = tid & 63;
  const int lg = lane >> 4, lq = lane & 15;
  const int bm = blockIdx.y * 128, bn = blockIdx.x * 128;
  const int wm = (wv >> 1) * 64, wn = (wv & 1) * 64;
  const int r0 = wv * 16 + (lane >> 2);   // staging row within pass
  const int kk = (lane & 3) * 8;          // staging k within pass

  f32x4 acc[4][4] = {};

  for (int k0 = 0; k0 < K; k0 += 32) {
#pragma unroll
    for (int p = 0; p < 2; p++) {
      int r = p * 64 + r0;
      __builtin_amdgcn_global_load_lds(
          (const __attribute__((address_space(1))) void*)(A + (size_t)(bm + r) * K + k0 + kk),
          (__attribute__((address_space(3))) void*)((char*)As + p * 4096 + wv * 1024),
          16, 0, 0);
      __builtin_amdgcn_global_load_lds(
          (const __attribute__((address_space(1))) void*)(Bt + (size_t)(bn + r) * K + k0 + kk),
          (__attribute__((address_space(3))) void*)((char*)Bs + p * 4096 + wv * 1024),
          16, 0, 0);
    }
    __syncthreads();
    short8 a[4], b[4];
#pragma unroll
    for (int f = 0; f < 4; f++) {
      a[f] = *(const short8*)&As[(wm + f * 16 + lq) * 32 + lg * 8];
      b[f] = *(const short8*)&Bs[(wn + f * 16 + lq) * 32 + lg * 8];
    }
#pragma unroll
    for (int i = 0; i < 4; i++)
#pragma unroll
      for (int j = 0; j < 4; j++)
        acc[i][j] = __builtin_amdgcn_mfma_f32_16x16x32_bf16(a[i], b[j], acc[i][j], 0, 0, 0);
    __syncthreads();
  }

#pragma unroll
  for (int i = 0; i < 4; i++)
#pragma unroll
    for (int j = 0; j < 4; j++) {
      int row = bm + wm + i * 16 + lg * 4;
      int col = bn + wn + j * 16 + lq;
#pragma unroll
      for (int t = 0; t < 4; t++) {
        float v = acc[i][j][t];
        if (OUT_BF16)
          ((unsigned short*)Cout)[(size_t)(row + t) * N + col] = f2bf(v);
        else
          ((float*)Cout)[(size_t)(row + t) * N + col] = v;
      }
    }
}

// ---------------- flash attention, 1 wave/block, QBLK=32, KVBLK=32 -----------
// swapped QK^T: st = mfma(K_rows, Q^T) -> S^T[kv][q]; tanh soft-cap bounds
// scores to +/-30 so softmax uses a FIXED max (no running max / no O-rescale).
__device__ __forceinline__ float softcap(float s) {
  float x = s * (ATTN_MULT / MAX_ATTN);
  x = fminf(fmaxf(x, -15.f), 15.f);
  float e = __expf(2.0f * x);
  return MAX_ATTN * ((e - 1.0f) / (e + 1.0f));
}

__global__ __launch_bounds__(64) void k_attn(const unsigned short* __restrict__ qkv,
                                             const unsigned short* __restrict__ vT,
                                             unsigned short* __restrict__ out) {
  const int lane = threadIdx.x;
  const int lg = lane >> 4, lq = lane & 15;
  const int q0 = (S_ / 32 - 1 - (int)blockIdx.x) * 32;  // long blocks first
  const int h = blockIdx.y;
  const int b = blockIdx.z;
  const int kh = h >> 2;   // GQA groups = 4

  const unsigned short* Qb = qkv + (size_t)(b * S_) * QKVN + h * HD_;
  const unsigned short* Kb = qkv + (size_t)(b * S_) * QKVN + D_ + kh * HD_;
  const unsigned short* Vt = vT + (size_t)(b * KVH_ + kh) * HD_ * S_;

  short8 qf[2][4];
#pragma unroll
  for (int u = 0; u < 2; u++)
#pragma unroll
    for (int c = 0; c < 4; c++)
      qf[u][c] = *(const short8*)(Qb + (size_t)(q0 + u * 16 + lq) * QKVN + c * 32 + lg * 8);

  float l[2] = {0.f, 0.f};
  f32x4 o[2][8] = {};

  const int kv_end = q0 + 32;
  for (int kv0 = 0; kv0 < kv_end; kv0 += 32) {
    short8 ka[2][4];
#pragma unroll
    for (int sI = 0; sI < 2; sI++)
#pragma unroll
      for (int c = 0; c < 4; c++)
        ka[sI][c] = *(const short8*)(Kb + (size_t)(kv0 + sI * 16 + lq) * QKVN + c * 32 + lg * 8);

    short8 vf[8];
#pragma unroll
    for (int fd = 0; fd < 8; fd++)
      vf[fd] = *(const short8*)(Vt + (size_t)(fd * 16 + lq) * S_ + kv0 + lg * 8);

#pragma unroll
    for (int u = 0; u < 2; u++) {
      f32x4 stA = {}, stB = {};
#pragma unroll
      for (int c = 0; c < 4; c++) {
        stA = __builtin_amdgcn_mfma_f32_16x16x32_bf16(ka[0][c], qf[u][c], stA, 0, 0, 0);
        stB = __builtin_amdgcn_mfma_f32_16x16x32_bf16(ka[1][c], qf[u][c], stB, 0, 0, 0);
      }
      // lane holds S^T[kv0 + lg*4 + i][q0 + u*16 + lq] (stA) and +16 (stB)
      const int gq = q0 + u * 16 + lq;
      float p[8], ps = 0.f;
#pragma unroll
      for (int i = 0; i < 4; i++) {
        float wa = (kv0 + lg * 4 + i > gq)      ? -1e30f : softcap(stA[i]);
        float wb = (kv0 + 16 + lg * 4 + i > gq) ? -1e30f : softcap(stB[i]);
        p[i]     = __expf(wa - MAX_ATTN);   // scores bounded by +/-30 -> fixed max
        p[4 + i] = __expf(wb - MAX_ATTN);
      }
#pragma unroll
      for (int i = 0; i < 8; i++) ps += p[i];
      ps += __shfl_xor(ps, 16);
      ps += __shfl_xor(ps, 32);
      l[u] += ps;

      // P exchange -> A-frag: lane needs P[lq][kv0 + 8*lg + j], j=0..7
      uint32_t a01 = packbf(p[0], p[1]), a23 = packbf(p[2], p[3]);
      uint32_t b01 = packbf(p[4], p[5]), b23 = packbf(p[6], p[7]);
      int g0 = (lg & 1) << 1;
      int src0 = (g0 << 4) | lq;
      int src1 = ((g0 + 1) << 4) | lq;
      uint32_t wA0 = __shfl(a01, src0, 64), wB0 = __shfl(b01, src0, 64);
      uint32_t wA1 = __shfl(a23, src0, 64), wB1 = __shfl(b23, src0, 64);
      uint32_t wA2 = __shfl(a01, src1, 64), wB2 = __shfl(b01, src1, 64);
      uint32_t wA3 = __shfl(a23, src1, 64), wB3 = __shfl(b23, src1, 64);
      bool useB = lg >= 2;
      union { short8 v; uint32_t w4[4]; } pa;
      pa.w4[0] = useB ? wB0 : wA0;
      pa.w4[1] = useB ? wB1 : wA1;
      pa.w4[2] = useB ? wB2 : wA2;
      pa.w4[3] = useB ? wB3 : wA3;
#pragma unroll
      for (int fd = 0; fd < 8; fd++)
        o[u][fd] = __builtin_amdgcn_mfma_f32_16x16x32_bf16(pa.v, vf[fd], o[u][fd], 0, 0, 0);
    }
  }

#pragma unroll
  for (int u = 0; u < 2; u++) {
    float li[4];
#pragma unroll
    for (int t = 0; t < 4; t++)
      li[t] = __shfl(l[u], (lane & 48) + lg * 4 + t, 64);
#pragma unroll
    for (int fd = 0; fd < 8; fd++)
#pragma unroll
      for (int t = 0; t < 4; t++) {
        int row = q0 + u * 16 + lg * 4 + t;
        int col = h * HD_ + fd * 16 + lq;
        out[(size_t)(b * S_ + row) * OHD + col] = f2bf(o[u][fd][t] / li[t]);
      }
  }
}

// ---------------------------------------------------------------------------
extern "C" void kernel_launch(void* const* d_in, const int* in_sizes, int n_in,
                              void* d_out, int out_size, void* d_ws, size_t ws_size,
                              hipStream_t stream) {
  const float* hs = (const float*)d_in[0];
  const float* Wq = (const float*)d_in[3];
  const float* Wk = (const float*)d_in[4];
  const float* Wv = (const float*)d_in[5];
  const float* Wo = (const float*)d_in[6];

  char* ws = (char*)d_ws;
  unsigned short* WqkvT = (unsigned short*)ws;                         // 48MB; reused as WoT
  unsigned short* hsb   = (unsigned short*)(ws + 50331648);            // 32MB; reused as attn_out
  float2* cs            = (float2*)(ws + 50331648 + 33554432);         // 1MB
  unsigned short* qkv   = (unsigned short*)d_out;                      // 48MB inside d_out (64MB)
  unsigned short* vT    = (unsigned short*)((char*)d_out + 50331648);  // 8MB in d_out slack
  unsigned short* WoT   = WqkvT;
  unsigned short* attn  = hsb;

  k_cstab<<<dim3((S_ * 64) / 256), 256, 0, stream>>>(cs);
  k_transpose<<<dim3(4096 / 32, 4096 / 32), dim3(32, 8), 0, stream>>>(Wq, WqkvT, 4096, 4096);
  k_transpose<<<dim3(1024 / 32, 4096 / 32), dim3(32, 8), 0, stream>>>(Wk, WqkvT + (size_t)4096 * 4096, 4096, 1024);
  k_transpose<<<dim3(1024 / 32, 4096 / 32), dim3(32, 8), 0, stream>>>(Wv, WqkvT + (size_t)5120 * 4096, 4096, 1024);
  k_cvt<<<2048, 256, 0, stream>>>(hs, hsb, (B_ * S_ * D_) / 4);
  k_gemm<true><<<dim3(QKVN / 128, (B_ * S_) / 128), 256, 0, stream>>>(hsb, WqkvT, qkv, B_ * S_, QKVN, D_);
  k_rope<<<dim3(B_ * S_, 10), 256, 0, stream>>>(qkv, cs);
  k_vt<<<dim3(1024 / 32, S_ / 32, B_), dim3(32, 8), 0, stream>>>(qkv, vT);
  k_transpose<<<dim3(4096 / 32, 4096 / 32), dim3(32, 8), 0, stream>>>(Wo, WoT, 4096, 4096);
  k_attn<<<dim3(S_ / 32, H_, B_), 64, 0, stream>>>(qkv, vT, attn);
  k_gemm<false><<<dim3(D_ / 128, (B_ * S_) / 128), 256, 0, stream>>>(attn, WoT, d_out, B_ * S_, D_, D_);
}